// Round 13
// baseline (140.460 us; speedup 1.0000x reference)
//
#include <hip/hip_runtime.h>

#define NQ 32768
#define NC 8192
#define CFEAT 128
#define CSPLIT 16
#define TILE (NC / CSPLIT)   // 512 coords per split
#define NPAIR (TILE / 2)     // 256 pairs per split
#define BLK 256
#define QPW 16               // queries per wave (phase 1)
#define QPB1 64              // queries per block (4 waves x 16)
#define GX (NQ / QPB1)       // 512 -> phase-1 grid (512, 16) = 8192 blocks

// ws: [0, 2 MB) f32 bestd[NQ][CSPLIT]; then float4 ctab[NC] (128 KB).
//
// NUMERICS IS FROZEN (R3/R4 lesson): per-coord distance chain is exactly
//   t = mul(-2cx, qx); t = fma(-2cy, qy, t); t = fma(-2cz, qz, t); d = cc + t
// with cc = ((cx*cx + cy*cy) + cz*cz) pinned by asm barriers. Flip-free vs
// np's argmin (R0/R2/R5/R6/R7/R10/R11/R12: absmax 0.0). pk halves run this
// exact IEEE-RN sequence with the {c0,c1} pairing (R12-proven bits). Phase 2
// consumes the SAME stored ctab bits (R1 lesson) via the same scalar chain.
//
// STRUCTURE LESSONS (counter-backed):
//  - R10: no in-loop index tracking (2.5x VALU). Min-only + equality rescan.
//  - R12: uniform GLOBAL ctab reads don't become s_load (coherence with
//    in-kernel writes) -> 48 us latency-bound. LDS broadcast version ~33 us
//    = VALU ~15 + LDS-pipe ~20 (128 broadcast ds_read_b128/wave, one
//    entry per instruction). R13 fix: DISTRIBUTED reads — one ds_read_b128
//    delivers 64 entries (one per lane); queries duplicated across lanes in
//    registers; per-query cross-lane fmin shfl reduce (exact). 64x fewer
//    LDS instructions, same VALU.
//  - R5: phase 2 stays wave-per-query, 8192 blocks (max TLP).
//  - R8: no cooperative launch / occupancy queries in kernel_launch.
#define BESTD_OFF 0
#define CTAB_OFF ((size_t)NQ * CSPLIT * 4)

typedef float f32x2 __attribute__((ext_vector_type(2)));

// Phase 1: per-split min DISTANCE only. Each wave: 16 register-resident
// queries (same on all lanes); lane l covers pairs {l, l+64, l+128, l+192}
// of the split (coords 2p, 2p+1 per pair). Inner body per pair per query:
// pk_mul + pk_fma + pk_fma + pk_add + v_min3 = 5 insts (R12-proven bits).
__global__ __launch_bounds__(BLK, 4) void argmin_split(
    const float* __restrict__ coords, const float* __restrict__ points,
    float* __restrict__ bestd, float4* __restrict__ ctab) {
  __shared__ float4 sA[NPAIR];      // (x0,x1,y0,y1) per pair
  __shared__ float4 sB[NPAIR];      // (z0,z1,w0,w1) per pair
  __shared__ float spts[QPB1 * 3];

  const int s = blockIdx.y;
  const int base = s * TILE;
  const int t = threadIdx.x;
  const int q0 = blockIdx.x * QPB1;

  // Stage pair t = coords (base+2t, base+2t+1): compute ctab entries once,
  // pair-interleave into LDS; block x==0 persists exact bits for phase 2.
  {
    const float2* c2 = (const float2*)coords;
    const int j0 = (base / 2) * 3 + 3 * t;    // float2 index of coord base+2t
    const float2 f0 = c2[j0 + 0];             // c0x c0y
    const float2 f1 = c2[j0 + 1];             // c0z c1x
    const float2 f2 = c2[j0 + 2];             // c1y c1z
    const float c0x = f0.x, c0y = f0.y, c0z = f1.x;
    const float c1x = f1.y, c1y = f2.x, c1z = f2.y;
    float xx0 = c0x * c0x, yy0 = c0y * c0y, zz0 = c0z * c0z;
    float xx1 = c1x * c1x, yy1 = c1y * c1y, zz1 = c1z * c1z;
    asm volatile("" : "+v"(xx0), "+v"(yy0), "+v"(zz0));   // pin cc order
    asm volatile("" : "+v"(xx1), "+v"(yy1), "+v"(zz1));
    const float cc0 = (xx0 + yy0) + zz0;
    const float cc1 = (xx1 + yy1) + zz1;
    const float4 e0 = make_float4(-2.0f * c0x, -2.0f * c0y, -2.0f * c0z, cc0);
    const float4 e1 = make_float4(-2.0f * c1x, -2.0f * c1y, -2.0f * c1z, cc1);
    sA[t] = make_float4(e0.x, e1.x, e0.y, e1.y);
    sB[t] = make_float4(e0.z, e1.z, e0.w, e1.w);
    if (blockIdx.x == 0) {
      const int i0 = base + 2 * t;
      ctab[i0] = e0;                 // same registers -> same bits as LDS
      ctab[i0 + 1] = e1;
    }
  }
  if (t < QPB1 * 3) spts[t] = points[q0 * 3 + t];   // 64 queries, coalesced
  __syncthreads();

  const int w = t >> 6, l = t & 63;

  float qx[QPW], qy[QPW], qz[QPW], best[QPW];
  #pragma unroll
  for (int j = 0; j < QPW; ++j) {
    const int jj = (w * QPW + j) * 3;      // wave-uniform LDS broadcast
    qx[j] = spts[jj + 0];
    qy[j] = spts[jj + 1];
    qz[j] = spts[jj + 2];
    best[j] = __builtin_inff();
  }

  #pragma unroll
  for (int i = 0; i < NPAIR / 64; ++i) {   // 4 iters: 2 distributed b128 each
    const float4 a = sA[l + 64 * i];       // 64 pairs per instruction
    const float4 b = sB[l + 64 * i];
    const f32x2 X = {a.x, a.y}, Y = {a.z, a.w};
    const f32x2 Z = {b.x, b.y}, W = {b.z, b.w};
    #pragma unroll
    for (int j = 0; j < QPW; ++j) {
      f32x2 tt = X * (f32x2){qx[j], qx[j]};                     // pk_mul (RN)
      tt = __builtin_elementwise_fma(Y, (f32x2){qy[j], qy[j]}, tt);  // pk_fma
      tt = __builtin_elementwise_fma(Z, (f32x2){qz[j], qz[j]}, tt);  // pk_fma
      const f32x2 d = W + tt;                                   // pk_add (RN)
      best[j] = fminf(fminf(best[j], d.x), d.y);                // v_min3_f32
    }
  }

  // Cross-lane exact fmin per query; lane j keeps query j's result; one
  // coalesced-ish store by lanes 0..15 (static j -> no dynamic reg index).
  float myv = __builtin_inff();
  #pragma unroll
  for (int j = 0; j < QPW; ++j) {
    float m = best[j];
    #pragma unroll
    for (int off = 32; off; off >>= 1) m = fminf(m, __shfl_xor(m, off, 64));
    myv = (l == j) ? m : myv;
  }
  if (l < QPW) bestd[(size_t)(q0 + w * QPW + l) * CSPLIT + s] = myv;
}

// Phase 2: one wave per query (8192 blocks — max TLP, R5 lesson).
// Reduce 16 split-mins (lanes >=16 hold +inf) -> m; lowest split attaining
// m via ballot/ffs; equality-rescan its 512 coords from global ctab with
// lane l covering coords 8l..8l+7 (frozen scalar chain on the same bits ->
// hit guaranteed; lowest lane then lowest j = global first index). Gather
// the 128-float feature row with 64 lanes x float2.
__global__ __launch_bounds__(256) void rescan_gather(
    const float4* __restrict__ ctab, const float* __restrict__ points,
    const float* __restrict__ bestd, const float* __restrict__ feature,
    float2* __restrict__ out) {
  const int q = blockIdx.x * 4 + (threadIdx.x >> 6);
  const int l = threadIdx.x & 63;

  const float v = (l < CSPLIT) ? bestd[(size_t)q * CSPLIT + l]
                               : __builtin_inff();
  float m = v;
  #pragma unroll
  for (int off = 32; off; off >>= 1) m = fminf(m, __shfl_xor(m, off, 64));
  const unsigned long long bs = __ballot(v == m);
  const int sstar = __ffsll(bs) - 1;        // lowest split attaining min

  const float qx = points[q * 3 + 0];       // wave-uniform
  const float qy = points[q * 3 + 1];
  const float qz = points[q * 3 + 2];
  const int b2 = sstar * TILE;

  float d[8];
  #pragma unroll
  for (int j = 0; j < 8; ++j) {
    const float4 c = ctab[b2 + 8 * l + j];
    float tt = __fmul_rn(c.x, qx);                  // FROZEN CHAIN
    tt = __fmaf_rn(c.y, qy, tt);
    tt = __fmaf_rn(c.z, qz, tt);
    d[j] = __fadd_rn(c.w, tt);
  }

  unsigned mm = 0;
  #pragma unroll
  for (int j = 0; j < 8; ++j) mm |= (d[j] == m) ? (1u << j) : 0u;
  const unsigned long long lb = __ballot(mm != 0);
  int idx;
  if (lb) {
    const int lstar = __ffsll(lb) - 1;        // lowest lane with a match
    const int jfirst = __ffs(mm) - 1;         // lowest matching j (per lane)
    const int jstar = __shfl(jfirst, lstar, 64);
    idx = b2 + 8 * lstar + jstar;
  } else {
    // Defense in depth (should be unreachable): true argmin over the 512
    // rescanned candidates, first-index tiebreak.
    float dm = d[0];
    int jm = 0;
    #pragma unroll
    for (int j = 1; j < 8; ++j) {
      if (d[j] < dm) { dm = d[j]; jm = j; }
    }
    float rd = dm;
    int ri = 8 * l + jm;
    #pragma unroll
    for (int off = 32; off; off >>= 1) {
      const float od = __shfl_xor(rd, off, 64);
      const int oi = __shfl_xor(ri, off, 64);
      if (od < rd || (od == rd && oi < ri)) { rd = od; ri = oi; }
    }
    idx = b2 + ri;
  }

  const float2* fr = (const float2*)(feature + (size_t)idx * CFEAT);
  out[(size_t)q * (CFEAT / 2) + l] = fr[l];
}

extern "C" void kernel_launch(void* const* d_in, const int* in_sizes, int n_in,
                              void* d_out, int out_size, void* d_ws, size_t ws_size,
                              hipStream_t stream) {
  const float* coords  = (const float*)d_in[0];   // [8192, 3]
  const float* feature = (const float*)d_in[1];   // [8192, 128]
  const float* points  = (const float*)d_in[2];   // [32768, 3]
  float2* out = (float2*)d_out;                   // [32768, 128]

  float* bestd = (float*)((char*)d_ws + BESTD_OFF);
  float4* ctab = (float4*)((char*)d_ws + CTAB_OFF);

  dim3 grid1(GX, CSPLIT);                         // (512, 16) = 8192 blocks
  argmin_split<<<grid1, BLK, 0, stream>>>(coords, points, bestd, ctab);

  rescan_gather<<<NQ / 4, 256, 0, stream>>>(ctab, points, bestd, feature,
                                            out);
}

// Round 14
// 98.267 us; speedup vs baseline: 1.4294x; 1.4294x over previous
//
#include <hip/hip_runtime.h>

#define NQ 32768
#define NC 8192
#define CFEAT 128
#define CSPLIT 64
#define TILE (NC / CSPLIT)   // 128 coords per split
#define BLK 256
#define QPT 4                // queries per thread (QPT ladder: 4=98 best)
#define QPB (BLK * QPT)      // 1024 queries per block
#define GX (NQ / QPB)        // 32 -> phase-1 grid (32, 64) = 2048 blocks

// ws layout: [0, 8 MB) f32 bestd[NQ][CSPLIT]; then float4 ctab[NC] (128 KB).
//
// NUMERICS IS FROZEN (R3/R4 lesson): per-coord distance chain is exactly
//   t = mul(-2cx, px); t = fma(-2cy, py, t); t = fma(-2cz, pz, t); d = cc + t
// with cc = ((cx*cx + cy*cy) + cz*cz) pinned by asm barrier. Flip-free vs
// np's argmin across 8 passing rounds. pk halves run this exact IEEE-RN
// sequence. Phase 2 reads the SAME stored ctab bits (R1 lesson).
//
// STRUCTURE LESSONS (counter-backed):
//  - R10: no in-loop index tracking (2.5x). Min-only + equality rescan.
//  - R12: uniform global ctab reads stay VMEM (48 us). R13: lane-distributed
//    reads + per-query shfl reduce = worse (53 us). LDS broadcast stands.
//  - R12-R13 VALU calibration: measured VALU-busy ~= 2.2x hand count, and
//    VGPR_Count=28 shows the compiler REMATERIALIZES the (f32x2){px,px}
//    splat pairs every iteration (6 movs per 5 useful insts). R14 fix:
//    build splat pairs ONCE, pin with asm so they cannot be remat'd ->
//    inner loop is pure pk+min3. VGPR ~50, still <=64 (8 waves/SIMD).
//  - R5: phase 2 stays wave-per-query, 8192 blocks (max TLP).
//  - R8: no cooperative launch / occupancy queries in kernel_launch.
#define BESTD_OFF 0
#define CTAB_OFF ((size_t)NQ * CSPLIT * 4)

typedef float f32x2 __attribute__((ext_vector_type(2)));

// Phase 1: per-split min DISTANCE only — no index tracking.
// Pair-interleaved LDS ctab (R6-proven): sA[p]=(x0,x1,y0,y1),
// sB[p]=(z0,z1,w0,w1) -> direct pk operands. Inner loop per 2 coords per
// query: v_pk_mul + v_pk_fma + v_pk_fma + v_pk_add + v_min3 = 5 insts,
// and with pinned splat pairs NOTHING else.
__global__ __launch_bounds__(BLK, 4) void argmin_split(
    const float* __restrict__ coords, const float* __restrict__ points,
    float* __restrict__ bestd, float4* __restrict__ ctab) {
  __shared__ float4 sA[TILE / 2];
  __shared__ float4 sB[TILE / 2];

  const int s = blockIdx.y;
  const int base = s * TILE;

  if (threadIdx.x < TILE) {
    const int i = base + threadIdx.x;
    const float cx = coords[i * 3 + 0];
    const float cy = coords[i * 3 + 1];
    const float cz = coords[i * 3 + 2];
    float xx = cx * cx, yy = cy * cy, zz = cz * cz;
    // Opaque barrier: forbid contracting these products into the adds.
    asm volatile("" : "+v"(xx), "+v"(yy), "+v"(zz));
    const float cc = (xx + yy) + zz;
    const float4 e = make_float4(-2.0f * cx, -2.0f * cy, -2.0f * cz, cc);
    const int p = threadIdx.x >> 1, hi = threadIdx.x & 1;
    float* a = (float*)&sA[p];
    float* b = (float*)&sB[p];
    a[0 + hi] = e.x;  a[2 + hi] = e.y;
    b[0 + hi] = e.z;  b[2 + hi] = e.w;
    if (blockIdx.x == 0) ctab[i] = e;   // persist exact bits for phase 2
  }

  const int q0 = blockIdx.x * QPB + threadIdx.x;
  f32x2 pxs[QPT], pys[QPT], pzs[QPT];
  float best[QPT];
  #pragma unroll
  for (int k = 0; k < QPT; ++k) {
    const int q = q0 + k * BLK;
    const float x = points[q * 3 + 0];
    const float y = points[q * 3 + 1];
    const float z = points[q * 3 + 2];
    pxs[k] = (f32x2){x, x};
    pys[k] = (f32x2){y, y};
    pzs[k] = (f32x2){z, z};
    // Pin each splat pair into a live VGPR pair: the compiler can no longer
    // prove halves equal, so it CANNOT rematerialize them inside the loop
    // (the R12/R13-diagnosed 2x VALU bloat). Values are unchanged.
    asm volatile("" : "+v"(pxs[k]), "+v"(pys[k]), "+v"(pzs[k]));
    best[k] = __builtin_inff();
  }
  __syncthreads();

  #pragma unroll 2
  for (int p = 0; p < TILE / 2; ++p) {
    const float4 a = sA[p];          // uniform addr -> broadcast ds_read_b128
    const float4 b = sB[p];
    const f32x2 X = {a.x, a.y}, Y = {a.z, a.w};
    const f32x2 Z = {b.x, b.y}, W = {b.z, b.w};
    #pragma unroll
    for (int k = 0; k < QPT; ++k) {
      f32x2 t = X * pxs[k];                            // v_pk_mul_f32 (RN)
      t = __builtin_elementwise_fma(Y, pys[k], t);     // v_pk_fma_f32 (RN)
      t = __builtin_elementwise_fma(Z, pzs[k], t);     // v_pk_fma_f32 (RN)
      const f32x2 d = W + t;                           // v_pk_add_f32 (RN)
      best[k] = fminf(fminf(best[k], d.x), d.y);       // v_min3_f32 (exact)
    }
  }

  #pragma unroll
  for (int k = 0; k < QPT; ++k) {
    const int q = q0 + k * BLK;
    bestd[(size_t)q * CSPLIT + s] = best[k];
  }
}

// Phase 2 (R2-proven, verbatim): one wave per query — reduce 64 split-mins
// (shfl min + ballot/ffs -> lowest winning split); equality-rescan that
// split's 128 coords from the SHARED global ctab (same bits + same frozen
// scalar chain as the pk halves -> hit guaranteed; first match = lowest
// coord). Tiebreak == np.argmin's global first-index. Gather feature row,
// 64 lanes x float2.
__global__ __launch_bounds__(256) void rescan_gather(
    const float4* __restrict__ ctab, const float* __restrict__ points,
    const float* __restrict__ bestd, const float* __restrict__ feature,
    float2* __restrict__ out) {
  const int q = blockIdx.x * 4 + (threadIdx.x >> 6);
  const int l = threadIdx.x & 63;

  // lane l holds split l's min — 256 B coalesced read per wave
  const float v = bestd[(size_t)q * CSPLIT + l];
  float m = v;
  #pragma unroll
  for (int off = 32; off; off >>= 1) m = fminf(m, __shfl_xor(m, off, 64));
  const unsigned long long bs = __ballot(v == m);
  const int sstar = __ffsll(bs) - 1;            // lowest split attaining min

  const float qx = points[q * 3 + 0];           // wave-uniform
  const float qy = points[q * 3 + 1];
  const float qz = points[q * 3 + 2];
  const int b2 = sstar * TILE;

  const float4 c0 = ctab[b2 + l];               // coalesced, lanes consecutive
  const float4 c1 = ctab[b2 + 64 + l];
  float t0 = __fmul_rn(c0.x, qx);                      // FROZEN CHAIN (R2)
  t0 = __fmaf_rn(c0.y, qy, t0);
  t0 = __fmaf_rn(c0.z, qz, t0);
  const float d0 = __fadd_rn(c0.w, t0);
  float t1 = __fmul_rn(c1.x, qx);
  t1 = __fmaf_rn(c1.y, qy, t1);
  t1 = __fmaf_rn(c1.z, qz, t1);
  const float d1 = __fadd_rn(c1.w, t1);

  const unsigned long long b0 = __ballot(d0 == m);
  const unsigned long long b1 = __ballot(d1 == m);
  int off_in;
  if (b0 | b1) {
    off_in = b0 ? (__ffsll(b0) - 1) : (64 + __ffsll(b1) - 1);
  } else {
    // Defense in depth (should be unreachable): true argmin over the 128
    // rescanned candidates, first-index tiebreak.
    float dm = fminf(d0, d1);
    int im = (d0 <= d1) ? l : (64 + l);
    #pragma unroll
    for (int off = 32; off; off >>= 1) {
      const float od = __shfl_xor(dm, off, 64);
      const int oi = __shfl_xor(im, off, 64);
      if (od < dm || (od == dm && oi < im)) { dm = od; im = oi; }
    }
    off_in = im;
  }
  const int idx = b2 + off_in;

  const float2* fr = (const float2*)(feature + (size_t)idx * CFEAT);
  out[(size_t)q * (CFEAT / 2) + l] = fr[l];
}

extern "C" void kernel_launch(void* const* d_in, const int* in_sizes, int n_in,
                              void* d_out, int out_size, void* d_ws, size_t ws_size,
                              hipStream_t stream) {
  const float* coords  = (const float*)d_in[0];   // [8192, 3]
  const float* feature = (const float*)d_in[1];   // [8192, 128]
  const float* points  = (const float*)d_in[2];   // [32768, 3]
  float2* out = (float2*)d_out;                   // [32768, 128]

  float* bestd = (float*)((char*)d_ws + BESTD_OFF);
  float4* ctab = (float4*)((char*)d_ws + CTAB_OFF);

  dim3 grid1(GX, CSPLIT);                         // (32, 64) = 2048 blocks
  argmin_split<<<grid1, BLK, 0, stream>>>(coords, points, bestd, ctab);

  rescan_gather<<<NQ / 4, 256, 0, stream>>>(ctab, points, bestd, feature,
                                            out);
}